// Round 1
// baseline (10036.797 us; speedup 1.0000x reference)
//
#include <hip/hip_runtime.h>
#include <hip/hip_bf16.h>
#include <stdint.h>

typedef __attribute__((ext_vector_type(4))) float f32x4;
typedef __attribute__((ext_vector_type(2))) float f32x2;
typedef __attribute__((ext_vector_type(8))) short s16x8;
typedef __attribute__((ext_vector_type(4))) uint32_t u32x4;
typedef __hip_bfloat16 bf16;

#define NBLK 128

__device__ __forceinline__ float sigf(float x){ return 1.f/(1.f+__expf(-x)); }
__device__ __forceinline__ float tanh_f(float x){ float e=__expf(2.f*x); return (e-1.f)/(e+1.f); }

// Device-wide barrier: monotonically increasing counter, sense-free.
// Requires all NBLK blocks co-resident (128 blocks x 256 thr, ~38KB LDS -> yes).
__device__ __forceinline__ void grid_barrier(uint32_t* cnt, uint32_t target){
  __syncthreads();
  if (threadIdx.x == 0) {
    __threadfence();  // release: make h/c writes device-visible
    __hip_atomic_fetch_add(cnt, 1u, __ATOMIC_RELAXED, __HIP_MEMORY_SCOPE_AGENT);
    while (__hip_atomic_load(cnt, __ATOMIC_RELAXED, __HIP_MEMORY_SCOPE_AGENT) < target)
      __builtin_amdgcn_s_sleep(2);
    __threadfence();  // acquire: invalidate stale L1/L2 lines for this CU
  }
  __syncthreads();
}

// ---------------- convert f32 -> bf16 ----------------
__global__ __launch_bounds__(256) void k_convert(const float* __restrict__ in, bf16* __restrict__ outp, int n){
  int i = (blockIdx.x*256 + threadIdx.x)*4;
  if (i >= n) return;
  f32x4 v = *(const f32x4*)&in[i];
  alignas(8) bf16 tmp[4] = {__float2bfloat16(v.x), __float2bfloat16(v.y), __float2bfloat16(v.z), __float2bfloat16(v.w)};
  *(uint64_t*)&outp[i] = *(const uint64_t*)tmp;
}

// ---------------- encoder embedding gather -> Xe[t*16+b][e] (bf16) ----------------
__global__ __launch_bounds__(256) void k_embed(const int* __restrict__ enc_in, const float* __restrict__ emb,
                                               bf16* __restrict__ Xe){
  int i = blockIdx.x*256 + threadIdx.x;   // 0 .. 1048575 (x4 elems)
  int o = i*4;
  int row = o >> 9, e = o & 511;
  int t = row >> 4, b = row & 15;
  int tok = enc_in[b*512 + t];
  f32x4 v = *(const f32x4*)&emb[(size_t)tok*512 + e];
  alignas(8) bf16 tmp[4] = {__float2bfloat16(v.x), __float2bfloat16(v.y), __float2bfloat16(v.z), __float2bfloat16(v.w)};
  *(uint64_t*)&Xe[o] = *(const uint64_t*)tmp;
}

// ---------------- bf16 MFMA GEMM: C[M][N] = A[M][K] * B[N][K]^T + bias ----------------
// 128x128 tile, BK=32, 4 waves (64x64 each), 16x16x32 mfma, reg-staged LDS with prefetch.
template<int OUT_BF16>
__global__ __launch_bounds__(256) void k_gemm(
    const bf16* __restrict__ A, const bf16* __restrict__ Bm,
    const float* __restrict__ bias1, const float* __restrict__ bias2,
    void* __restrict__ Cp, int M, int N, int K)
{
  __shared__ bf16 Al[128*32];
  __shared__ bf16 Bl[128*32];
  const int tid = threadIdx.x;
  const int n0 = blockIdx.x*128, m0 = blockIdx.y*128;
  const int wv = tid >> 6, lane = tid & 63;
  const int wr = (wv >> 1)*64, wc = (wv & 1)*64;
  const int lrow = lane & 15, lk = (lane >> 4)*8;
  const int r1 = tid >> 2, kq = (tid & 3)*8;

  f32x4 acc[4][4];
  #pragma unroll
  for (int i=0;i<4;++i)
    #pragma unroll
    for (int j=0;j<4;++j) { f32x4 z = {0.f,0.f,0.f,0.f}; acc[i][j] = z; }

  const bf16* pa0 = &A[(size_t)(m0 + r1)*K + kq];
  const bf16* pa1 = &A[(size_t)(m0 + 64 + r1)*K + kq];
  const bf16* pb0 = &Bm[(size_t)(n0 + r1)*K + kq];
  const bf16* pb1 = &Bm[(size_t)(n0 + 64 + r1)*K + kq];

  u32x4 a0 = *(const u32x4*)pa0, a1 = *(const u32x4*)pa1;
  u32x4 b0 = *(const u32x4*)pb0, b1 = *(const u32x4*)pb1;

  const int nk = K >> 5;
  for (int kt = 0; kt < nk; ++kt) {
    __syncthreads();
    *(u32x4*)&Al[r1*32 + kq]        = a0;
    *(u32x4*)&Al[(64 + r1)*32 + kq] = a1;
    *(u32x4*)&Bl[r1*32 + kq]        = b0;
    *(u32x4*)&Bl[(64 + r1)*32 + kq] = b1;
    __syncthreads();
    if (kt + 1 < nk) {
      int off = (kt+1)*32;
      a0 = *(const u32x4*)(pa0 + off); a1 = *(const u32x4*)(pa1 + off);
      b0 = *(const u32x4*)(pb0 + off); b1 = *(const u32x4*)(pb1 + off);
    }
    s16x8 af[4], bfr[4];
    #pragma unroll
    for (int mi=0;mi<4;++mi) af[mi]  = *(const s16x8*)&Al[(wr + mi*16 + lrow)*32 + lk];
    #pragma unroll
    for (int ni=0;ni<4;++ni) bfr[ni] = *(const s16x8*)&Bl[(wc + ni*16 + lrow)*32 + lk];
    #pragma unroll
    for (int mi=0;mi<4;++mi)
      #pragma unroll
      for (int ni=0;ni<4;++ni)
        acc[mi][ni] = __builtin_amdgcn_mfma_f32_16x16x32_bf16(af[mi], bfr[ni], acc[mi][ni], 0, 0, 0);
  }
  const int crow = (lane >> 4)*4;
  #pragma unroll
  for (int mi=0;mi<4;++mi) {
    #pragma unroll
    for (int ni=0;ni<4;++ni) {
      int cc = n0 + wc + ni*16 + lrow;
      float badd = (bias1 ? bias1[cc] : 0.f) + (bias2 ? bias2[cc] : 0.f);
      #pragma unroll
      for (int q=0;q<4;++q) {
        int rr = m0 + wr + mi*16 + crow + q;
        float v = acc[mi][ni][q] + badd;
        if (OUT_BF16) ((bf16*)Cp)[(size_t)rr*N + cc] = __float2bfloat16(v);
        else          ((float*)Cp)[(size_t)rr*N + cc] = v;
      }
    }
  }
}

// ---------------- encoder recurrence: 512 sequential steps ----------------
// 128 blocks x 256 thr. Block owns 4 j's (16 gate cols). thread = (col_l in 0..15, ksl in 0..15).
// w_hh slice lives in registers (step-invariant); h reloaded to LDS each step.
__global__ __launch_bounds__(256) void k_encoder(
    const bf16* __restrict__ GXe, const float* __restrict__ w_hh,
    float* __restrict__ h_glob, float* __restrict__ c_glob,
    float* __restrict__ enc_out, uint32_t* __restrict__ cnt)
{
  const int tid = threadIdx.x, bid = blockIdx.x;
  const int col_l = tid & 15, ksl = tid >> 4;
  const int colg = (col_l >> 2)*512 + bid*4 + (col_l & 3);
  const int lane = tid & 63, wvi = tid >> 6;

  __shared__ float h_lds[16*512];
  __shared__ float red2[4*16*17];
  __shared__ float gate_lds[256];
  __shared__ float c_l[64];

  f32x4 wreg[8];
  #pragma unroll
  for (int i = 0; i < 8; ++i) {
    int kk = (i + ksl) & 7;   // bank-rotated load order; matched at use site
    wreg[i] = *(const f32x4*)&w_hh[colg*512 + ksl*32 + kk*4];
  }
  if (tid < 64) c_l[tid] = 0.f;

  const int rb = tid & 15, rcol = tid >> 4;
  const int rcolg = (rcol >> 2)*512 + bid*4 + (rcol & 3);

  uint32_t bar = 0;
  for (int t = 0; t < 512; ++t) {
    #pragma unroll
    for (int q = 0; q < 8; ++q) {
      int fi = q*256 + tid;
      *(f32x4*)&h_lds[fi*4] = *(const f32x4*)&h_glob[fi*4];
    }
    __syncthreads();
    #pragma unroll
    for (int b = 0; b < 16; ++b) {
      float s0=0.f,s1=0.f,s2=0.f,s3=0.f;
      #pragma unroll
      for (int i = 0; i < 8; ++i) {
        int kk = (i + ksl) & 7;
        f32x4 hv = *(const f32x4*)&h_lds[b*512 + ksl*32 + kk*4];
        s0 = __fmaf_rn(hv.x, wreg[i].x, s0);
        s1 = __fmaf_rn(hv.y, wreg[i].y, s1);
        s2 = __fmaf_rn(hv.z, wreg[i].z, s2);
        s3 = __fmaf_rn(hv.w, wreg[i].w, s3);
      }
      float v = (s0+s1)+(s2+s3);
      v += __shfl_xor(v, 16);
      v += __shfl_xor(v, 32);
      if (lane < 16) red2[wvi*272 + b*17 + lane] = v;
    }
    __syncthreads();
    {
      float s = red2[0*272 + rb*17 + rcol] + red2[1*272 + rb*17 + rcol]
              + red2[2*272 + rb*17 + rcol] + red2[3*272 + rb*17 + rcol];
      s += __bfloat162float(GXe[(size_t)(t*16 + rb)*2048 + rcolg]);
      gate_lds[rb*16 + rcol] = s;
    }
    __syncthreads();
    if (tid < 64) {
      int b = tid & 15, j2 = tid >> 4;
      float gi = gate_lds[b*16 + j2];
      float gf = gate_lds[b*16 + 4 + j2];
      float gg = gate_lds[b*16 + 8 + j2];
      float go = gate_lds[b*16 + 12 + j2];
      float c  = c_l[tid];
      float cn = sigf(gf)*c + sigf(gi)*tanh_f(gg);
      float hn = sigf(go)*tanh_f(cn);
      c_l[tid] = cn;
      int jgl = bid*4 + j2;
      h_glob[b*512 + jgl] = hn;
      enc_out[((size_t)b*512 + t)*512 + jgl] = hn;
    }
    bar += NBLK;
    grid_barrier(cnt, bar);
  }
  if (tid < 64) {
    int b = tid & 15, j2 = tid >> 4;
    c_glob[b*512 + bid*4 + j2] = c_l[tid];
  }
}

// ---------------- gates for decoder step 0: x0 @ w_ih^T + hT @ w_hh^T + biases ----------------
__global__ __launch_bounds__(128) void k_gates0(
    const int* __restrict__ dec_in, const float* __restrict__ emb,
    const float* __restrict__ hT,
    const float* __restrict__ w_ih, const float* __restrict__ w_hh,
    const float* __restrict__ b_ih, const float* __restrict__ b_hh,
    float* __restrict__ g0)
{
  int gt = blockIdx.x*128 + threadIdx.x;  // 0..32767
  int b = gt & 15, col = gt >> 4;
  const float* x0 = &emb[(size_t)dec_in[b*128] * 512];
  const float* hp = &hT[b*512];
  const float* wi = &w_ih[(size_t)col*512];
  const float* wh = &w_hh[(size_t)col*512];
  float s0=0.f, s1=0.f;
  for (int k = 0; k < 512; k += 4) {
    f32x4 xv = *(const f32x4*)&x0[k]; f32x4 wv = *(const f32x4*)&wi[k];
    f32x4 hv = *(const f32x4*)&hp[k]; f32x4 w2 = *(const f32x4*)&wh[k];
    s0 += xv.x*wv.x + xv.y*wv.y + xv.z*wv.z + xv.w*wv.w;
    s1 += hv.x*w2.x + hv.y*w2.y + hv.z*w2.z + hv.w*w2.w;
  }
  g0[b*2048 + col] = s0 + s1 + b_ih[col] + b_hh[col];
}

// ---------------- decoder recurrence: 128 sequential steps (x_t == h_t for t>=1) ----------------
__global__ __launch_bounds__(256) void k_decoder(
    const float* __restrict__ w_ih, const float* __restrict__ w_hh,
    const float* __restrict__ b_ih, const float* __restrict__ b_hh,
    const float* __restrict__ gates0,
    float* __restrict__ h_glob, const float* __restrict__ c_glob,
    float* __restrict__ dec_h, bf16* __restrict__ dec_out,
    uint32_t* __restrict__ cnt)
{
  const int tid = threadIdx.x, bid = blockIdx.x;
  const int col_l = tid & 15, ksl = tid >> 4;
  const int colg = (col_l >> 2)*512 + bid*4 + (col_l & 3);
  const int lane = tid & 63, wvi = tid >> 6;

  __shared__ float h_lds[16*512];
  __shared__ float red2[4*16*17];
  __shared__ float gate_lds[256];
  __shared__ float c_l[64];

  f32x4 wreg[8];
  #pragma unroll
  for (int i = 0; i < 8; ++i) {
    int kk = (i + ksl) & 7;
    int o = colg*512 + ksl*32 + kk*4;
    f32x4 wa = *(const f32x4*)&w_ih[o];
    f32x4 wb = *(const f32x4*)&w_hh[o];
    wreg[i] = wa + wb;
  }
  if (tid < 64) {
    int b = tid & 15, j2 = tid >> 4;
    c_l[tid] = c_glob[b*512 + bid*4 + j2];
  }
  const int rb = tid & 15, rcol = tid >> 4;
  const int rcolg = (rcol >> 2)*512 + bid*4 + (rcol & 3);
  const float bias_r = b_ih[rcolg] + b_hh[rcolg];

  uint32_t bar = 0;
  for (int t = 0; t < 128; ++t) {
    if (t > 0) {
      #pragma unroll
      for (int q = 0; q < 8; ++q) {
        int fi = q*256 + tid;
        *(f32x4*)&h_lds[fi*4] = *(const f32x4*)&h_glob[fi*4];
      }
      __syncthreads();
      #pragma unroll
      for (int b = 0; b < 16; ++b) {
        float s0=0.f,s1=0.f,s2=0.f,s3=0.f;
        #pragma unroll
        for (int i = 0; i < 8; ++i) {
          int kk = (i + ksl) & 7;
          f32x4 hv = *(const f32x4*)&h_lds[b*512 + ksl*32 + kk*4];
          s0 = __fmaf_rn(hv.x, wreg[i].x, s0);
          s1 = __fmaf_rn(hv.y, wreg[i].y, s1);
          s2 = __fmaf_rn(hv.z, wreg[i].z, s2);
          s3 = __fmaf_rn(hv.w, wreg[i].w, s3);
        }
        float v = (s0+s1)+(s2+s3);
        v += __shfl_xor(v, 16);
        v += __shfl_xor(v, 32);
        if (lane < 16) red2[wvi*272 + b*17 + lane] = v;
      }
    }
    __syncthreads();
    {
      float s;
      if (t == 0) {
        s = gates0[rb*2048 + rcolg];
      } else {
        s = red2[0*272 + rb*17 + rcol] + red2[1*272 + rb*17 + rcol]
          + red2[2*272 + rb*17 + rcol] + red2[3*272 + rb*17 + rcol] + bias_r;
      }
      gate_lds[rb*16 + rcol] = s;
    }
    __syncthreads();
    if (tid < 64) {
      int b = tid & 15, j2 = tid >> 4;
      float gi = gate_lds[b*16 + j2];
      float gf = gate_lds[b*16 + 4 + j2];
      float gg = gate_lds[b*16 + 8 + j2];
      float go = gate_lds[b*16 + 12 + j2];
      float c  = c_l[tid];
      float cn = sigf(gf)*c + sigf(gi)*tanh_f(gg);
      float hn = sigf(go)*tanh_f(cn);
      c_l[tid] = cn;
      int jgl = bid*4 + j2;
      h_glob[b*512 + jgl] = hn;
      dec_h[((size_t)t*16 + b)*512 + jgl] = hn;
      dec_out[((size_t)(b*128 + t))*1024 + jgl] = __float2bfloat16(hn);
    }
    bar += NBLK;
    grid_barrier(cnt, bar);
  }
}

// ---------------- batched attention over all (t,b): scores -> softmax -> ctx ----------------
// grid: 128 blocks = 16 b x 8 t-groups(16 t each); 256 threads.
__global__ __launch_bounds__(256) void k_attn(
    const float* __restrict__ dec_h, const float* __restrict__ enc_out,
    bf16* __restrict__ dOut)
{
  const int tid = threadIdx.x, bid = blockIdx.x;
  const int b = bid >> 3, t0 = (bid & 7)*16;
  __shared__ float h16[16*512];
  __shared__ float sc[16*512];
  #pragma unroll
  for (int q = 0; q < 8; ++q) {
    int fi = q*256 + tid;
    int tt = fi >> 7, e4 = (fi & 127)*4;
    *(f32x4*)&h16[tt*512 + e4] = *(const f32x4*)&dec_h[((size_t)(t0 + tt)*16 + b)*512 + e4];
  }
  __syncthreads();
  const float* encb = &enc_out[(size_t)b*512*512];
  for (int si = 0; si < 2; ++si) {
    int s = si*256 + tid;
    float a[16];
    #pragma unroll
    for (int tt=0;tt<16;++tt) a[tt]=0.f;
    for (int e4 = 0; e4 < 512; e4 += 4) {
      f32x4 ev = *(const f32x4*)&encb[(size_t)s*512 + e4];
      #pragma unroll
      for (int tt = 0; tt < 16; ++tt) {
        f32x4 hv = *(const f32x4*)&h16[tt*512 + e4];
        a[tt] += ev.x*hv.x + ev.y*hv.y + ev.z*hv.z + ev.w*hv.w;
      }
    }
    #pragma unroll
    for (int tt=0;tt<16;++tt) sc[tt*512 + s] = a[tt];
  }
  __syncthreads();
  {
    int wv = tid >> 6, lane = tid & 63;
    #pragma unroll
    for (int u = 0; u < 4; ++u) {
      int tt = wv*4 + u;
      float x[8];
      float m = -1e30f;
      #pragma unroll
      for (int i=0;i<8;++i){ x[i] = sc[tt*512 + i*64 + lane]; m = fmaxf(m, x[i]); }
      #pragma unroll
      for (int off=1; off<64; off<<=1) m = fmaxf(m, __shfl_xor(m, off));
      float sum = 0.f;
      #pragma unroll
      for (int i=0;i<8;++i){ x[i] = __expf(x[i]-m); sum += x[i]; }
      #pragma unroll
      for (int off=1; off<64; off<<=1) sum += __shfl_xor(sum, off);
      float inv = 1.f/sum;
      #pragma unroll
      for (int i=0;i<8;++i) sc[tt*512 + i*64 + lane] = x[i]*inv;
    }
  }
  __syncthreads();
  {
    int e0 = tid*2;
    float cx[16], cy[16];
    #pragma unroll
    for (int tt=0;tt<16;++tt){ cx[tt]=0.f; cy[tt]=0.f; }
    for (int s = 0; s < 512; ++s) {
      f32x2 ev = *(const f32x2*)&encb[(size_t)s*512 + e0];
      #pragma unroll
      for (int tt = 0; tt < 16; ++tt) {
        float aw = sc[tt*512 + s];
        cx[tt] += aw*ev.x; cy[tt] += aw*ev.y;
      }
    }
    #pragma unroll
    for (int tt = 0; tt < 16; ++tt) {
      size_t rowo = ((size_t)(b*128 + t0 + tt))*1024 + 512 + e0;
      alignas(4) bf16 tmp[2] = {__float2bfloat16(cx[tt]), __float2bfloat16(cy[tt])};
      *(uint32_t*)&dOut[rowo] = *(const uint32_t*)tmp;
    }
  }
}

// ---------------- host ----------------
extern "C" void kernel_launch(void* const* d_in, const int* in_sizes, int n_in,
                              void* d_out, int out_size, void* d_ws, size_t ws_size,
                              hipStream_t stream)
{
  const int*   enc_in = (const int*)d_in[0];
  const int*   dec_in = (const int*)d_in[1];
  const float* emb    = (const float*)d_in[2];
  const float* w_ih_e = (const float*)d_in[3];
  const float* w_hh_e = (const float*)d_in[4];
  const float* b_ih_e = (const float*)d_in[5];
  const float* b_hh_e = (const float*)d_in[6];
  const float* w_ih_d = (const float*)d_in[7];
  const float* w_hh_d = (const float*)d_in[8];
  const float* b_ih_d = (const float*)d_in[9];
  const float* b_hh_d = (const float*)d_in[10];
  const float* w_proj = (const float*)d_in[11];
  const float* b_proj = (const float*)d_in[12];
  float* out = (float*)d_out;

  char* ws = (char*)d_ws;
  size_t off = 0;
  auto alloc = [&](size_t bytes)->void* { void* p = ws + off; off += (bytes + 255) & ~(size_t)255; return p; };
  bf16*  Wp      = (bf16*)alloc(32000ull*1024*2);
  bf16*  Xe      = (bf16*)alloc(8192ull*512*2);
  bf16*  Wie     = (bf16*)alloc(2048ull*512*2);
  bf16*  GXe     = (bf16*)alloc(8192ull*2048*2);
  float* enc_out = (float*)alloc(16ull*512*512*4);
  float* dec_h   = (float*)alloc(128ull*16*512*4);
  bf16*  dOutB   = (bf16*)alloc(2048ull*1024*2);
  float* h_g     = (float*)alloc(16*512*4);
  float* c_g     = (float*)alloc(16*512*4);
  float* g0      = (float*)alloc(16*2048*4);
  uint32_t* cnts = (uint32_t*)alloc(256);
  if (off > ws_size) return;  // workspace too small -> fail validation loudly

  (void)hipMemsetAsync(cnts, 0, 256, stream);
  (void)hipMemsetAsync(h_g, 0, 16*512*4, stream);

  k_convert<<<32000, 256, 0, stream>>>(w_proj, Wp, 32768000);
  k_convert<<<1024, 256, 0, stream>>>(w_ih_e, Wie, 1048576);
  k_embed<<<4096, 256, 0, stream>>>(enc_in, emb, Xe);
  // encoder input gates for all timesteps: GXe = Xe @ w_ih_e^T + (b_ih_e + b_hh_e)
  k_gemm<1><<<dim3(16, 64), 256, 0, stream>>>(Xe, Wie, b_ih_e, b_hh_e, GXe, 8192, 2048, 512);
  k_encoder<<<NBLK, 256, 0, stream>>>(GXe, w_hh_e, h_g, c_g, enc_out, cnts);
  k_gates0<<<256, 128, 0, stream>>>(dec_in, emb, h_g, w_ih_d, w_hh_d, b_ih_d, b_hh_d, g0);
  k_decoder<<<NBLK, 256, 0, stream>>>(w_ih_d, w_hh_d, b_ih_d, b_hh_d, g0, h_g, c_g, dec_h, dOutB, cnts + 16);
  k_attn<<<128, 256, 0, stream>>>(dec_h, enc_out, dOutB);
  // logits = dec_out @ w_proj^T + b_proj
  k_gemm<0><<<dim3(250, 16), 256, 0, stream>>>(dOutB, Wp, b_proj, nullptr, out, 2048, 32000, 1024);
}

// Round 2
// 8072.038 us; speedup vs baseline: 1.2434x; 1.2434x over previous
//
#include <hip/hip_runtime.h>
#include <hip/hip_bf16.h>
#include <stdint.h>

typedef __attribute__((ext_vector_type(4))) float f32x4;
typedef __attribute__((ext_vector_type(2))) float f32x2;
typedef __attribute__((ext_vector_type(8))) short s16x8;
typedef __attribute__((ext_vector_type(4))) uint32_t u32x4;
typedef __hip_bfloat16 bf16;

#define NBLK 128

__device__ __forceinline__ float sigf(float x){ return 1.f/(1.f+__expf(-x)); }
__device__ __forceinline__ float tanh_f(float x){ float e=__expf(2.f*x); return (e-1.f)/(e+1.f); }

// Coherent (device-scope, sc1) helpers — no fences, no RMW.
__device__ __forceinline__ void st_f32_agent(float* p, float v){
  __hip_atomic_store(p, v, __ATOMIC_RELAXED, __HIP_MEMORY_SCOPE_AGENT);
}
__device__ __forceinline__ uint64_t ld_u64_agent(const uint64_t* p){
  return __hip_atomic_load(p, __ATOMIC_RELAXED, __HIP_MEMORY_SCOPE_AGENT);
}
__device__ __forceinline__ void st_u32_agent(uint32_t* p, uint32_t v){
  __hip_atomic_store(p, v, __ATOMIC_RELAXED, __HIP_MEMORY_SCOPE_AGENT);
}

// Wave-0 poll: wait until all 128 per-block flags are >= tgt.
// flags viewed as u64[64]; lane i checks flags[2i], flags[2i+1]. One load per iter.
__device__ __forceinline__ void poll_flags(const uint32_t* flags, uint32_t tgt){
  const uint64_t* f64 = (const uint64_t*)flags;
  int lane = threadIdx.x & 63;
  uint32_t spins = 0;
  for(;;){
    uint64_t v = ld_u64_agent(&f64[lane]);
    bool ok = ((uint32_t)v >= tgt) && ((uint32_t)(v >> 32) >= tgt);
    if (__all(ok)) break;
    __builtin_amdgcn_s_sleep(1);
    if (++spins > (1u<<20)) break;  // bail out of a broken protocol -> visible failure
  }
}

// ---------------- convert f32 -> bf16 ----------------
__global__ __launch_bounds__(256) void k_convert(const float* __restrict__ in, bf16* __restrict__ outp, int n){
  int i = (blockIdx.x*256 + threadIdx.x)*4;
  if (i >= n) return;
  f32x4 v = *(const f32x4*)&in[i];
  alignas(8) bf16 tmp[4] = {__float2bfloat16(v.x), __float2bfloat16(v.y), __float2bfloat16(v.z), __float2bfloat16(v.w)};
  *(uint64_t*)&outp[i] = *(const uint64_t*)tmp;
}

// ---------------- encoder embedding gather -> Xe[t*16+b][e] (bf16) ----------------
__global__ __launch_bounds__(256) void k_embed(const int* __restrict__ enc_in, const float* __restrict__ emb,
                                               bf16* __restrict__ Xe){
  int i = blockIdx.x*256 + threadIdx.x;
  int o = i*4;
  int row = o >> 9, e = o & 511;
  int t = row >> 4, b = row & 15;
  int tok = enc_in[b*512 + t];
  f32x4 v = *(const f32x4*)&emb[(size_t)tok*512 + e];
  alignas(8) bf16 tmp[4] = {__float2bfloat16(v.x), __float2bfloat16(v.y), __float2bfloat16(v.z), __float2bfloat16(v.w)};
  *(uint64_t*)&Xe[o] = *(const uint64_t*)tmp;
}

// ---------------- bf16 MFMA GEMM: C[M][N] = A[M][K] * B[N][K]^T + bias ----------------
template<int OUT_BF16>
__global__ __launch_bounds__(256) void k_gemm(
    const bf16* __restrict__ A, const bf16* __restrict__ Bm,
    const float* __restrict__ bias1, const float* __restrict__ bias2,
    void* __restrict__ Cp, int M, int N, int K)
{
  __shared__ bf16 Al[128*32];
  __shared__ bf16 Bl[128*32];
  const int tid = threadIdx.x;
  const int n0 = blockIdx.x*128, m0 = blockIdx.y*128;
  const int wv = tid >> 6, lane = tid & 63;
  const int wr = (wv >> 1)*64, wc = (wv & 1)*64;
  const int lrow = lane & 15, lk = (lane >> 4)*8;
  const int r1 = tid >> 2, kq = (tid & 3)*8;

  f32x4 acc[4][4];
  #pragma unroll
  for (int i=0;i<4;++i)
    #pragma unroll
    for (int j=0;j<4;++j) { f32x4 z = {0.f,0.f,0.f,0.f}; acc[i][j] = z; }

  const bf16* pa0 = &A[(size_t)(m0 + r1)*K + kq];
  const bf16* pa1 = &A[(size_t)(m0 + 64 + r1)*K + kq];
  const bf16* pb0 = &Bm[(size_t)(n0 + r1)*K + kq];
  const bf16* pb1 = &Bm[(size_t)(n0 + 64 + r1)*K + kq];

  u32x4 a0 = *(const u32x4*)pa0, a1 = *(const u32x4*)pa1;
  u32x4 b0 = *(const u32x4*)pb0, b1 = *(const u32x4*)pb1;

  const int nk = K >> 5;
  for (int kt = 0; kt < nk; ++kt) {
    __syncthreads();
    *(u32x4*)&Al[r1*32 + kq]        = a0;
    *(u32x4*)&Al[(64 + r1)*32 + kq] = a1;
    *(u32x4*)&Bl[r1*32 + kq]        = b0;
    *(u32x4*)&Bl[(64 + r1)*32 + kq] = b1;
    __syncthreads();
    if (kt + 1 < nk) {
      int off = (kt+1)*32;
      a0 = *(const u32x4*)(pa0 + off); a1 = *(const u32x4*)(pa1 + off);
      b0 = *(const u32x4*)(pb0 + off); b1 = *(const u32x4*)(pb1 + off);
    }
    s16x8 af[4], bfr[4];
    #pragma unroll
    for (int mi=0;mi<4;++mi) af[mi]  = *(const s16x8*)&Al[(wr + mi*16 + lrow)*32 + lk];
    #pragma unroll
    for (int ni=0;ni<4;++ni) bfr[ni] = *(const s16x8*)&Bl[(wc + ni*16 + lrow)*32 + lk];
    #pragma unroll
    for (int mi=0;mi<4;++mi)
      #pragma unroll
      for (int ni=0;ni<4;++ni)
        acc[mi][ni] = __builtin_amdgcn_mfma_f32_16x16x32_bf16(af[mi], bfr[ni], acc[mi][ni], 0, 0, 0);
  }
  const int crow = (lane >> 4)*4;
  #pragma unroll
  for (int mi=0;mi<4;++mi) {
    #pragma unroll
    for (int ni=0;ni<4;++ni) {
      int cc = n0 + wc + ni*16 + lrow;
      float badd = (bias1 ? bias1[cc] : 0.f) + (bias2 ? bias2[cc] : 0.f);
      #pragma unroll
      for (int q=0;q<4;++q) {
        int rr = m0 + wr + mi*16 + crow + q;
        float v = acc[mi][ni][q] + badd;
        if (OUT_BF16) ((bf16*)Cp)[(size_t)rr*N + cc] = __float2bfloat16(v);
        else          ((float*)Cp)[(size_t)rr*N + cc] = v;
      }
    }
  }
}

// ---------------- encoder recurrence: 512 sequential steps ----------------
// Fence-free flag protocol. h double-buffered in h_buf[2][16][512].
// Step t: (t>0) poll flags>=t, read h from buf[t&1]; compute; write h_{t+1} to
// buf[(t+1)&1] via sc1 stores; s_waitcnt vmcnt(0); flags[bid]=t+1.
__global__ __launch_bounds__(256) void k_encoder(
    const bf16* __restrict__ GXe, const float* __restrict__ w_hh,
    float* __restrict__ h_buf, float* __restrict__ c_glob,
    float* __restrict__ enc_out, uint32_t* __restrict__ flags)
{
  const int tid = threadIdx.x, bid = blockIdx.x;
  const int col_l = tid & 15, ksl = tid >> 4;
  const int colg = (col_l >> 2)*512 + bid*4 + (col_l & 3);
  const int lane = tid & 63, wvi = tid >> 6;

  __shared__ float h_lds[16*512];
  __shared__ float red2[4*16*17];
  __shared__ float gate_lds[256];
  __shared__ float c_l[64];

  f32x4 wreg[8];
  #pragma unroll
  for (int i = 0; i < 8; ++i) {
    int kk = (i + ksl) & 7;   // bank-rotated load order; matched at use site
    wreg[i] = *(const f32x4*)&w_hh[colg*512 + ksl*32 + kk*4];
  }
  if (tid < 64) c_l[tid] = 0.f;

  const int rb = tid & 15, rcol = tid >> 4;
  const int rcolg = (rcol >> 2)*512 + bid*4 + (rcol & 3);

  for (int t = 0; t < 512; ++t) {
    if (t > 0) {
      if (wvi == 0) poll_flags(flags, (uint32_t)t);
      __syncthreads();
      const uint64_t* hg64 = (const uint64_t*)(h_buf + (t & 1)*8192);
      uint64_t* hl64 = (uint64_t*)h_lds;
      #pragma unroll
      for (int q = 0; q < 16; ++q)
        hl64[q*256 + tid] = ld_u64_agent(&hg64[q*256 + tid]);
      __syncthreads();
      #pragma unroll
      for (int b = 0; b < 16; ++b) {
        float s0=0.f,s1=0.f,s2=0.f,s3=0.f;
        #pragma unroll
        for (int i = 0; i < 8; ++i) {
          int kk = (i + ksl) & 7;
          f32x4 hv = *(const f32x4*)&h_lds[b*512 + ksl*32 + kk*4];
          s0 = __fmaf_rn(hv.x, wreg[i].x, s0);
          s1 = __fmaf_rn(hv.y, wreg[i].y, s1);
          s2 = __fmaf_rn(hv.z, wreg[i].z, s2);
          s3 = __fmaf_rn(hv.w, wreg[i].w, s3);
        }
        float v = (s0+s1)+(s2+s3);
        v += __shfl_xor(v, 16);
        v += __shfl_xor(v, 32);
        if (lane < 16) red2[wvi*272 + b*17 + lane] = v;
      }
    }
    __syncthreads();
    {
      float s = (t == 0) ? 0.f
              : red2[0*272 + rb*17 + rcol] + red2[1*272 + rb*17 + rcol]
              + red2[2*272 + rb*17 + rcol] + red2[3*272 + rb*17 + rcol];
      s += __bfloat162float(GXe[(size_t)(t*16 + rb)*2048 + rcolg]);
      gate_lds[rb*16 + rcol] = s;
    }
    __syncthreads();
    if (tid < 64) {
      int b = tid & 15, j2 = tid >> 4;
      float gi = gate_lds[b*16 + j2];
      float gf = gate_lds[b*16 + 4 + j2];
      float gg = gate_lds[b*16 + 8 + j2];
      float go = gate_lds[b*16 + 12 + j2];
      float c  = c_l[tid];
      float cn = sigf(gf)*c + sigf(gi)*tanh_f(gg);
      float hn = sigf(go)*tanh_f(cn);
      c_l[tid] = cn;
      int jgl = bid*4 + j2;
      st_f32_agent(&h_buf[((t+1) & 1)*8192 + b*512 + jgl], hn);
      enc_out[((size_t)b*512 + t)*512 + jgl] = hn;
    }
    if (tid == 0) {
      asm volatile("s_waitcnt vmcnt(0)" ::: "memory");
      st_u32_agent(&flags[bid], (uint32_t)(t + 1));
    }
  }
  if (tid < 64) {
    int b = tid & 15, j2 = tid >> 4;
    c_glob[b*512 + bid*4 + j2] = c_l[tid];
  }
}

// ---------------- gates for decoder step 0 ----------------
__global__ __launch_bounds__(128) void k_gates0(
    const int* __restrict__ dec_in, const float* __restrict__ emb,
    const float* __restrict__ hT,
    const float* __restrict__ w_ih, const float* __restrict__ w_hh,
    const float* __restrict__ b_ih, const float* __restrict__ b_hh,
    float* __restrict__ g0)
{
  int gt = blockIdx.x*128 + threadIdx.x;
  int b = gt & 15, col = gt >> 4;
  const float* x0 = &emb[(size_t)dec_in[b*128] * 512];
  const float* hp = &hT[b*512];
  const float* wi = &w_ih[(size_t)col*512];
  const float* wh = &w_hh[(size_t)col*512];
  float s0=0.f, s1=0.f;
  for (int k = 0; k < 512; k += 4) {
    f32x4 xv = *(const f32x4*)&x0[k]; f32x4 wv = *(const f32x4*)&wi[k];
    f32x4 hv = *(const f32x4*)&hp[k]; f32x4 w2 = *(const f32x4*)&wh[k];
    s0 += xv.x*wv.x + xv.y*wv.y + xv.z*wv.z + xv.w*wv.w;
    s1 += hv.x*w2.x + hv.y*w2.y + hv.z*w2.z + hv.w*w2.w;
  }
  g0[b*2048 + col] = s0 + s1 + b_ih[col] + b_hh[col];
}

// ---------------- decoder recurrence: 128 sequential steps (x_t == h_t for t>=1) ----------------
__global__ __launch_bounds__(256) void k_decoder(
    const float* __restrict__ w_ih, const float* __restrict__ w_hh,
    const float* __restrict__ b_ih, const float* __restrict__ b_hh,
    const float* __restrict__ gates0,
    float* __restrict__ h_buf, const float* __restrict__ c_glob,
    float* __restrict__ dec_h, bf16* __restrict__ dec_out,
    uint32_t* __restrict__ flags)
{
  const int tid = threadIdx.x, bid = blockIdx.x;
  const int col_l = tid & 15, ksl = tid >> 4;
  const int colg = (col_l >> 2)*512 + bid*4 + (col_l & 3);
  const int lane = tid & 63, wvi = tid >> 6;

  __shared__ float h_lds[16*512];
  __shared__ float red2[4*16*17];
  __shared__ float gate_lds[256];
  __shared__ float c_l[64];

  f32x4 wreg[8];
  #pragma unroll
  for (int i = 0; i < 8; ++i) {
    int kk = (i + ksl) & 7;
    int o = colg*512 + ksl*32 + kk*4;
    f32x4 wa = *(const f32x4*)&w_ih[o];
    f32x4 wb = *(const f32x4*)&w_hh[o];
    wreg[i] = wa + wb;
  }
  if (tid < 64) {
    int b = tid & 15, j2 = tid >> 4;
    c_l[tid] = c_glob[b*512 + bid*4 + j2];
  }
  const int rb = tid & 15, rcol = tid >> 4;
  const int rcolg = (rcol >> 2)*512 + bid*4 + (rcol & 3);
  const float bias_r = b_ih[rcolg] + b_hh[rcolg];

  for (int t = 0; t < 128; ++t) {
    if (t > 0) {
      if (wvi == 0) poll_flags(flags, (uint32_t)t);
      __syncthreads();
      const uint64_t* hg64 = (const uint64_t*)(h_buf + (t & 1)*8192);
      uint64_t* hl64 = (uint64_t*)h_lds;
      #pragma unroll
      for (int q = 0; q < 16; ++q)
        hl64[q*256 + tid] = ld_u64_agent(&hg64[q*256 + tid]);
      __syncthreads();
      #pragma unroll
      for (int b = 0; b < 16; ++b) {
        float s0=0.f,s1=0.f,s2=0.f,s3=0.f;
        #pragma unroll
        for (int i = 0; i < 8; ++i) {
          int kk = (i + ksl) & 7;
          f32x4 hv = *(const f32x4*)&h_lds[b*512 + ksl*32 + kk*4];
          s0 = __fmaf_rn(hv.x, wreg[i].x, s0);
          s1 = __fmaf_rn(hv.y, wreg[i].y, s1);
          s2 = __fmaf_rn(hv.z, wreg[i].z, s2);
          s3 = __fmaf_rn(hv.w, wreg[i].w, s3);
        }
        float v = (s0+s1)+(s2+s3);
        v += __shfl_xor(v, 16);
        v += __shfl_xor(v, 32);
        if (lane < 16) red2[wvi*272 + b*17 + lane] = v;
      }
    }
    __syncthreads();
    {
      float s;
      if (t == 0) {
        s = gates0[rb*2048 + rcolg];
      } else {
        s = red2[0*272 + rb*17 + rcol] + red2[1*272 + rb*17 + rcol]
          + red2[2*272 + rb*17 + rcol] + red2[3*272 + rb*17 + rcol] + bias_r;
      }
      gate_lds[rb*16 + rcol] = s;
    }
    __syncthreads();
    if (tid < 64) {
      int b = tid & 15, j2 = tid >> 4;
      float gi = gate_lds[b*16 + j2];
      float gf = gate_lds[b*16 + 4 + j2];
      float gg = gate_lds[b*16 + 8 + j2];
      float go = gate_lds[b*16 + 12 + j2];
      float c  = c_l[tid];
      float cn = sigf(gf)*c + sigf(gi)*tanh_f(gg);
      float hn = sigf(go)*tanh_f(cn);
      c_l[tid] = cn;
      int jgl = bid*4 + j2;
      st_f32_agent(&h_buf[((t+1) & 1)*8192 + b*512 + jgl], hn);
      dec_h[((size_t)t*16 + b)*512 + jgl] = hn;
      dec_out[((size_t)(b*128 + t))*1024 + jgl] = __float2bfloat16(hn);
    }
    if (tid == 0) {
      asm volatile("s_waitcnt vmcnt(0)" ::: "memory");
      st_u32_agent(&flags[bid], (uint32_t)(t + 1));
    }
  }
}

// ---------------- batched attention over all (t,b) ----------------
__global__ __launch_bounds__(256) void k_attn(
    const float* __restrict__ dec_h, const float* __restrict__ enc_out,
    bf16* __restrict__ dOut)
{
  const int tid = threadIdx.x, bid = blockIdx.x;
  const int b = bid >> 3, t0 = (bid & 7)*16;
  __shared__ float h16[16*512];
  __shared__ float sc[16*512];
  #pragma unroll
  for (int q = 0; q < 8; ++q) {
    int fi = q*256 + tid;
    int tt = fi >> 7, e4 = (fi & 127)*4;
    *(f32x4*)&h16[tt*512 + e4] = *(const f32x4*)&dec_h[((size_t)(t0 + tt)*16 + b)*512 + e4];
  }
  __syncthreads();
  const float* encb = &enc_out[(size_t)b*512*512];
  for (int si = 0; si < 2; ++si) {
    int s = si*256 + tid;
    float a[16];
    #pragma unroll
    for (int tt=0;tt<16;++tt) a[tt]=0.f;
    for (int e4 = 0; e4 < 512; e4 += 4) {
      f32x4 ev = *(const f32x4*)&encb[(size_t)s*512 + e4];
      #pragma unroll
      for (int tt = 0; tt < 16; ++tt) {
        f32x4 hv = *(const f32x4*)&h16[tt*512 + e4];
        a[tt] += ev.x*hv.x + ev.y*hv.y + ev.z*hv.z + ev.w*hv.w;
      }
    }
    #pragma unroll
    for (int tt=0;tt<16;++tt) sc[tt*512 + s] = a[tt];
  }
  __syncthreads();
  {
    int wv = tid >> 6, lane = tid & 63;
    #pragma unroll
    for (int u = 0; u < 4; ++u) {
      int tt = wv*4 + u;
      float x[8];
      float m = -1e30f;
      #pragma unroll
      for (int i=0;i<8;++i){ x[i] = sc[tt*512 + i*64 + lane]; m = fmaxf(m, x[i]); }
      #pragma unroll
      for (int off=1; off<64; off<<=1) m = fmaxf(m, __shfl_xor(m, off));
      float sum = 0.f;
      #pragma unroll
      for (int i=0;i<8;++i){ x[i] = __expf(x[i]-m); sum += x[i]; }
      #pragma unroll
      for (int off=1; off<64; off<<=1) sum += __shfl_xor(sum, off);
      float inv = 1.f/sum;
      #pragma unroll
      for (int i=0;i<8;++i) sc[tt*512 + i*64 + lane] = x[i]*inv;
    }
  }
  __syncthreads();
  {
    int e0 = tid*2;
    float cx[16], cy[16];
    #pragma unroll
    for (int tt=0;tt<16;++tt){ cx[tt]=0.f; cy[tt]=0.f; }
    for (int s = 0; s < 512; ++s) {
      f32x2 ev = *(const f32x2*)&encb[(size_t)s*512 + e0];
      #pragma unroll
      for (int tt = 0; tt < 16; ++tt) {
        float aw = sc[tt*512 + s];
        cx[tt] += aw*ev.x; cy[tt] += aw*ev.y;
      }
    }
    #pragma unroll
    for (int tt = 0; tt < 16; ++tt) {
      size_t rowo = ((size_t)(b*128 + t0 + tt))*1024 + 512 + e0;
      alignas(4) bf16 tmp[2] = {__float2bfloat16(cx[tt]), __float2bfloat16(cy[tt])};
      *(uint32_t*)&dOut[rowo] = *(const uint32_t*)tmp;
    }
  }
}

// ---------------- host ----------------
extern "C" void kernel_launch(void* const* d_in, const int* in_sizes, int n_in,
                              void* d_out, int out_size, void* d_ws, size_t ws_size,
                              hipStream_t stream)
{
  const int*   enc_in = (const int*)d_in[0];
  const int*   dec_in = (const int*)d_in[1];
  const float* emb    = (const float*)d_in[2];
  const float* w_ih_e = (const float*)d_in[3];
  const float* w_hh_e = (const float*)d_in[4];
  const float* b_ih_e = (const float*)d_in[5];
  const float* b_hh_e = (const float*)d_in[6];
  const float* w_ih_d = (const float*)d_in[7];
  const float* w_hh_d = (const float*)d_in[8];
  const float* b_ih_d = (const float*)d_in[9];
  const float* b_hh_d = (const float*)d_in[10];
  const float* w_proj = (const float*)d_in[11];
  const float* b_proj = (const float*)d_in[12];
  float* out = (float*)d_out;

  char* ws = (char*)d_ws;
  size_t off = 0;
  auto alloc = [&](size_t bytes)->void* { void* p = ws + off; off += (bytes + 255) & ~(size_t)255; return p; };
  bf16*  Wp      = (bf16*)alloc(32000ull*1024*2);
  bf16*  Xe      = (bf16*)alloc(8192ull*512*2);
  bf16*  Wie     = (bf16*)alloc(2048ull*512*2);
  bf16*  GXe     = (bf16*)alloc(8192ull*2048*2);
  float* enc_out = (float*)alloc(16ull*512*512*4);
  float* dec_h   = (float*)alloc(128ull*16*512*4);
  bf16*  dOutB   = (bf16*)alloc(2048ull*1024*2);
  float* h_buf   = (float*)alloc(2*16*512*4);      // double-buffered h
  float* c_g     = (float*)alloc(16*512*4);
  float* g0      = (float*)alloc(16*2048*4);
  uint32_t* flagsE = (uint32_t*)alloc(512);
  uint32_t* flagsD = (uint32_t*)alloc(512);
  if (off > ws_size) return;  // workspace too small -> fail validation loudly

  // zero: h buf0 (initial h state) + both flag arrays (contiguous-ish; 3 small memsets)
  (void)hipMemsetAsync(h_buf, 0, 2*16*512*4, stream);
  (void)hipMemsetAsync(flagsE, 0, 512, stream);
  (void)hipMemsetAsync(flagsD, 0, 512, stream);

  k_convert<<<32000, 256, 0, stream>>>(w_proj, Wp, 32768000);
  k_convert<<<1024, 256, 0, stream>>>(w_ih_e, Wie, 1048576);
  k_embed<<<4096, 256, 0, stream>>>(enc_in, emb, Xe);
  // encoder input gates for all timesteps: GXe = Xe @ w_ih_e^T + (b_ih_e + b_hh_e)
  k_gemm<1><<<dim3(16, 64), 256, 0, stream>>>(Xe, Wie, b_ih_e, b_hh_e, GXe, 8192, 2048, 512);
  k_encoder<<<NBLK, 256, 0, stream>>>(GXe, w_hh_e, h_buf, c_g, enc_out, flagsE);
  // final encoder h lands in h_buf[0] (t=511 writes buf (512&1)=0)
  k_gates0<<<256, 128, 0, stream>>>(dec_in, emb, h_buf, w_ih_d, w_hh_d, b_ih_d, b_hh_d, g0);
  k_decoder<<<NBLK, 256, 0, stream>>>(w_ih_d, w_hh_d, b_ih_d, b_hh_d, g0, h_buf, c_g, dec_h, dOutB, flagsD);
  k_attn<<<128, 256, 0, stream>>>(dec_h, enc_out, dOutB);
  // logits = dec_out @ w_proj^T + b_proj
  k_gemm<0><<<dim3(250, 16), 256, 0, stream>>>(dOutB, Wp, b_proj, nullptr, out, 2048, 32000, 1024);
}

// Round 3
// 4947.403 us; speedup vs baseline: 2.0287x; 1.6316x over previous
//
#include <hip/hip_runtime.h>
#include <hip/hip_bf16.h>
#include <stdint.h>

typedef __attribute__((ext_vector_type(4))) float f32x4;
typedef __attribute__((ext_vector_type(2))) float f32x2;
typedef __attribute__((ext_vector_type(8))) short s16x8;
typedef __attribute__((ext_vector_type(4))) uint32_t u32x4;
typedef __hip_bfloat16 bf16;

#define NBLK 64   // recurrence blocks; each owns 8 j-columns (32 gate-cols)

__device__ __forceinline__ float sigf(float x){ return 1.f/(1.f+__expf(-x)); }
__device__ __forceinline__ float tanh_f(float x){ float e=__expf(2.f*x); return (e-1.f)/(e+1.f); }

__device__ __forceinline__ void st_f32_agent(float* p, float v){
  __hip_atomic_store(p, v, __ATOMIC_RELAXED, __HIP_MEMORY_SCOPE_AGENT);
}
__device__ __forceinline__ uint64_t ld_u64_agent(const uint64_t* p){
  return __hip_atomic_load(p, __ATOMIC_RELAXED, __HIP_MEMORY_SCOPE_AGENT);
}
__device__ __forceinline__ void st_u32_agent(uint32_t* p, uint32_t v){
  __hip_atomic_store(p, v, __ATOMIC_RELAXED, __HIP_MEMORY_SCOPE_AGENT);
}

// Poll: lane i (i<64) watches block i's 128B-padded flag line (2 flags: one per
// producer wave). One u64 coherent load per lane per iteration.
__device__ __forceinline__ void poll_flags64(const uint32_t* flags, uint32_t tgt){
  const uint64_t* f64 = (const uint64_t*)flags;
  int lane = threadIdx.x & 63;
  uint32_t spins = 0;
  for(;;){
    uint64_t v = ld_u64_agent(&f64[lane*16]);   // byte offset lane*128
    bool ok = ((uint32_t)v >= tgt) && ((uint32_t)(v >> 32) >= tgt);
    if (__all(ok)) break;
    __builtin_amdgcn_s_sleep(1);
    if (++spins > (1u<<18)) break;  // broken protocol -> visible failure
  }
}

// ---------------- convert f32 -> bf16 ----------------
__global__ __launch_bounds__(256) void k_convert(const float* __restrict__ in, bf16* __restrict__ outp, int n){
  int i = (blockIdx.x*256 + threadIdx.x)*4;
  if (i >= n) return;
  f32x4 v = *(const f32x4*)&in[i];
  alignas(8) bf16 tmp[4] = {__float2bfloat16(v.x), __float2bfloat16(v.y), __float2bfloat16(v.z), __float2bfloat16(v.w)};
  *(uint64_t*)&outp[i] = *(const uint64_t*)tmp;
}

// ---------------- encoder embedding gather -> Xe[t*16+b][e] (bf16) ----------------
__global__ __launch_bounds__(256) void k_embed(const int* __restrict__ enc_in, const float* __restrict__ emb,
                                               bf16* __restrict__ Xe){
  int i = blockIdx.x*256 + threadIdx.x;
  int o = i*4;
  int row = o >> 9, e = o & 511;
  int t = row >> 4, b = row & 15;
  int tok = enc_in[b*512 + t];
  f32x4 v = *(const f32x4*)&emb[(size_t)tok*512 + e];
  alignas(8) bf16 tmp[4] = {__float2bfloat16(v.x), __float2bfloat16(v.y), __float2bfloat16(v.z), __float2bfloat16(v.w)};
  *(uint64_t*)&Xe[o] = *(const uint64_t*)tmp;
}

// ---------------- bf16 MFMA GEMM: C[M][N] = A[M][K] * B[N][K]^T + bias ----------------
template<int OUT_BF16>
__global__ __launch_bounds__(256) void k_gemm(
    const bf16* __restrict__ A, const bf16* __restrict__ Bm,
    const float* __restrict__ bias1, const float* __restrict__ bias2,
    void* __restrict__ Cp, int M, int N, int K)
{
  __shared__ bf16 Al[128*32];
  __shared__ bf16 Bl[128*32];
  const int tid = threadIdx.x;
  const int n0 = blockIdx.x*128, m0 = blockIdx.y*128;
  const int wv = tid >> 6, lane = tid & 63;
  const int wr = (wv >> 1)*64, wc = (wv & 1)*64;
  const int lrow = lane & 15, lk = (lane >> 4)*8;
  const int r1 = tid >> 2, kq = (tid & 3)*8;

  f32x4 acc[4][4];
  #pragma unroll
  for (int i=0;i<4;++i)
    #pragma unroll
    for (int j=0;j<4;++j) { f32x4 z = {0.f,0.f,0.f,0.f}; acc[i][j] = z; }

  const bf16* pa0 = &A[(size_t)(m0 + r1)*K + kq];
  const bf16* pa1 = &A[(size_t)(m0 + 64 + r1)*K + kq];
  const bf16* pb0 = &Bm[(size_t)(n0 + r1)*K + kq];
  const bf16* pb1 = &Bm[(size_t)(n0 + 64 + r1)*K + kq];

  u32x4 a0 = *(const u32x4*)pa0, a1 = *(const u32x4*)pa1;
  u32x4 b0 = *(const u32x4*)pb0, b1 = *(const u32x4*)pb1;

  const int nk = K >> 5;
  for (int kt = 0; kt < nk; ++kt) {
    __syncthreads();
    *(u32x4*)&Al[r1*32 + kq]        = a0;
    *(u32x4*)&Al[(64 + r1)*32 + kq] = a1;
    *(u32x4*)&Bl[r1*32 + kq]        = b0;
    *(u32x4*)&Bl[(64 + r1)*32 + kq] = b1;
    __syncthreads();
    if (kt + 1 < nk) {
      int off = (kt+1)*32;
      a0 = *(const u32x4*)(pa0 + off); a1 = *(const u32x4*)(pa1 + off);
      b0 = *(const u32x4*)(pb0 + off); b1 = *(const u32x4*)(pb1 + off);
    }
    s16x8 af[4], bfr[4];
    #pragma unroll
    for (int mi=0;mi<4;++mi) af[mi]  = *(const s16x8*)&Al[(wr + mi*16 + lrow)*32 + lk];
    #pragma unroll
    for (int ni=0;ni<4;++ni) bfr[ni] = *(const s16x8*)&Bl[(wc + ni*16 + lrow)*32 + lk];
    #pragma unroll
    for (int mi=0;mi<4;++mi)
      #pragma unroll
      for (int ni=0;ni<4;++ni)
        acc[mi][ni] = __builtin_amdgcn_mfma_f32_16x16x32_bf16(af[mi], bfr[ni], acc[mi][ni], 0, 0, 0);
  }
  const int crow = (lane >> 4)*4;
  #pragma unroll
  for (int mi=0;mi<4;++mi) {
    #pragma unroll
    for (int ni=0;ni<4;++ni) {
      int cc = n0 + wc + ni*16 + lrow;
      float badd = (bias1 ? bias1[cc] : 0.f) + (bias2 ? bias2[cc] : 0.f);
      #pragma unroll
      for (int q=0;q<4;++q) {
        int rr = m0 + wr + mi*16 + crow + q;
        float v = acc[mi][ni][q] + badd;
        if (OUT_BF16) ((bf16*)Cp)[(size_t)rr*N + cc] = __float2bfloat16(v);
        else          ((float*)Cp)[(size_t)rr*N + cc] = v;
      }
    }
  }
}

// ---------------- encoder recurrence: 512 sequential steps ----------------
// 64 blocks x 512 threads. Block owns 8 j's (32 gate-cols).
// Exchange layout h_ex[2][64][128]: each block writes 4 FULL exclusive 128B lines.
// Flags: one 128B line per block, 2 flags (per producer wave, each after own vmcnt(0)).
// enc_out writes done by waves 2-3 AFTER the flag (off critical path).
__global__ __launch_bounds__(512) void k_encoder(
    const bf16* __restrict__ GXe, const float* __restrict__ w_hh,
    float* __restrict__ h_ex, float* __restrict__ c_glob,
    float* __restrict__ enc_out, uint32_t* __restrict__ flags)
{
  const int tid = threadIdx.x, bid = blockIdx.x;
  const int col_l = tid & 31, ksl = tid >> 5;              // 32 cols x 16 k-slices
  const int colg = (col_l >> 3)*512 + bid*8 + (col_l & 7); // gate*512 + j
  const int lane = tid & 63, wvi = tid >> 6;               // 8 waves

  __shared__ float h_lds[16*520];
  __shared__ float red2[8*512];
  __shared__ float gate_lds[16*33];
  __shared__ float h_out_l[128];

  f32x4 wreg[8];
  #pragma unroll
  for (int i = 0; i < 8; ++i) {
    int kk = (i + ksl) & 7;   // rotated; matched at use site
    wreg[i] = *(const f32x4*)&w_hh[(size_t)colg*512 + ksl*32 + kk*4];
  }
  float c_reg = 0.f;

  const int rb = tid >> 5, rcol = tid & 31;                 // final-reduce mapping
  const int rcolg = (rcol >> 3)*512 + bid*8 + (rcol & 7);
  const int pb = tid & 15, pjl = (tid >> 4) & 7;            // producer mapping (tid<128)
  const int ob = (tid - 128) & 15, ojl = ((tid - 128) >> 4) & 7;  // output waves (tid 128..255)

  for (int t = 0; t < 512; ++t) {
    float gx = __bfloat162float(GXe[(size_t)(t*16 + rb)*2048 + rcolg]);  // prefetch; hides under poll
    float s = gx;
    if (t > 0) {
      if (wvi == 0) poll_flags64(flags, (uint32_t)t);
      __syncthreads();                                       // (A)
      const uint64_t* hg = (const uint64_t*)(h_ex + (t & 1)*8192);
      #pragma unroll
      for (int q = 0; q < 8; ++q) {
        int u = q*512 + tid;                                 // u64 idx 0..4095
        uint64_t v = ld_u64_agent(&hg[u]);
        int bid2 = u >> 6, rem = u & 63, bb = rem >> 2, jh = rem & 3;
        *(uint64_t*)&h_lds[bb*520 + bid2*8 + jh*2] = v;
      }
      __syncthreads();                                       // (B)
      #pragma unroll
      for (int b = 0; b < 16; ++b) {
        float s0=0.f,s1=0.f,s2=0.f,s3=0.f;
        #pragma unroll
        for (int i = 0; i < 8; ++i) {
          int kk = (i + ksl) & 7;
          f32x4 hv = *(const f32x4*)&h_lds[b*520 + ksl*32 + kk*4];
          s0 = __fmaf_rn(hv.x, wreg[i].x, s0);
          s1 = __fmaf_rn(hv.y, wreg[i].y, s1);
          s2 = __fmaf_rn(hv.z, wreg[i].z, s2);
          s3 = __fmaf_rn(hv.w, wreg[i].w, s3);
        }
        float v = (s0+s1)+(s2+s3);
        v += __shfl_xor(v, 32);
        if (lane < 32) red2[wvi*512 + b*32 + lane] = v;
      }
      __syncthreads();                                       // (C)
      #pragma unroll
      for (int w = 0; w < 8; ++w) s += red2[w*512 + tid];
    }
    gate_lds[rb*33 + rcol] = s;
    __syncthreads();                                         // (D)
    if (tid < 128) {
      float gi = gate_lds[pb*33 +      pjl];
      float gf = gate_lds[pb*33 +  8 + pjl];
      float gg = gate_lds[pb*33 + 16 + pjl];
      float go = gate_lds[pb*33 + 24 + pjl];
      float cn = sigf(gf)*c_reg + sigf(gi)*tanh_f(gg);
      float hn = sigf(go)*tanh_f(cn);
      c_reg = cn;
      st_f32_agent(&h_ex[((t+1) & 1)*8192 + bid*128 + pb*8 + pjl], hn);
      h_out_l[tid] = hn;
      asm volatile("s_waitcnt vmcnt(0)" ::: "memory");       // ack covers ONLY this wave's h stores
      if (lane == 0) st_u32_agent(&flags[bid*32 + wvi], (uint32_t)(t + 1));
    }
    __syncthreads();                                         // (E)
    if (tid >= 128 && tid < 256) {
      float hn = h_out_l[tid - 128];
      enc_out[((size_t)ob*512 + t)*512 + bid*8 + ojl] = hn;  // off critical path
    }
  }
  if (tid < 128) c_glob[pb*512 + bid*8 + pjl] = c_reg;
}

// ---------------- gates for decoder step 0 (hT read from permuted h_ex[0]) ----------------
__global__ __launch_bounds__(128) void k_gates0(
    const int* __restrict__ dec_in, const float* __restrict__ emb,
    const float* __restrict__ hT,   // h_ex[0]: [64][128] = [k>>3][b*8 + (k&7)]
    const float* __restrict__ w_ih, const float* __restrict__ w_hh,
    const float* __restrict__ b_ih, const float* __restrict__ b_hh,
    float* __restrict__ g0)
{
  int gt = blockIdx.x*128 + threadIdx.x;
  int b = gt & 15, col = gt >> 4;
  const float* x0 = &emb[(size_t)dec_in[b*128] * 512];
  const float* wi = &w_ih[(size_t)col*512];
  const float* wh = &w_hh[(size_t)col*512];
  float s0=0.f, s1=0.f;
  for (int k8 = 0; k8 < 64; ++k8) {
    f32x4 h0 = *(const f32x4*)&hT[k8*128 + b*8];
    f32x4 h1 = *(const f32x4*)&hT[k8*128 + b*8 + 4];
    f32x4 x0v = *(const f32x4*)&x0[k8*8];
    f32x4 x1v = *(const f32x4*)&x0[k8*8 + 4];
    f32x4 wi0 = *(const f32x4*)&wi[k8*8];
    f32x4 wi1 = *(const f32x4*)&wi[k8*8 + 4];
    f32x4 wh0 = *(const f32x4*)&wh[k8*8];
    f32x4 wh1 = *(const f32x4*)&wh[k8*8 + 4];
    s0 += x0v.x*wi0.x + x0v.y*wi0.y + x0v.z*wi0.z + x0v.w*wi0.w
        + x1v.x*wi1.x + x1v.y*wi1.y + x1v.z*wi1.z + x1v.w*wi1.w;
    s1 += h0.x*wh0.x + h0.y*wh0.y + h0.z*wh0.z + h0.w*wh0.w
        + h1.x*wh1.x + h1.y*wh1.y + h1.z*wh1.z + h1.w*wh1.w;
  }
  g0[b*2048 + col] = s0 + s1 + b_ih[col] + b_hh[col];
}

// ---------------- decoder recurrence: 128 sequential steps (x_t == h_t for t>=1) ----------------
__global__ __launch_bounds__(512) void k_decoder(
    const float* __restrict__ w_ih, const float* __restrict__ w_hh,
    const float* __restrict__ b_ih, const float* __restrict__ b_hh,
    const float* __restrict__ gates0,
    float* __restrict__ h_ex, const float* __restrict__ c_glob,
    float* __restrict__ dec_h, bf16* __restrict__ dec_out,
    uint32_t* __restrict__ flags)
{
  const int tid = threadIdx.x, bid = blockIdx.x;
  const int col_l = tid & 31, ksl = tid >> 5;
  const int colg = (col_l >> 3)*512 + bid*8 + (col_l & 7);
  const int lane = tid & 63, wvi = tid >> 6;

  __shared__ float h_lds[16*520];
  __shared__ float red2[8*512];
  __shared__ float gate_lds[16*33];
  __shared__ float h_out_l[128];

  f32x4 wreg[8];
  #pragma unroll
  for (int i = 0; i < 8; ++i) {
    int kk = (i + ksl) & 7;
    size_t o = (size_t)colg*512 + ksl*32 + kk*4;
    f32x4 wa = *(const f32x4*)&w_ih[o];
    f32x4 wb = *(const f32x4*)&w_hh[o];
    wreg[i] = wa + wb;
  }
  const int rb = tid >> 5, rcol = tid & 31;
  const int rcolg = (rcol >> 3)*512 + bid*8 + (rcol & 7);
  const float bias_r = b_ih[rcolg] + b_hh[rcolg];
  const int pb = tid & 15, pjl = (tid >> 4) & 7;
  const int ob = (tid - 128) & 15, ojl = ((tid - 128) >> 4) & 7;

  float c_reg = 0.f;
  if (tid < 128) c_reg = c_glob[pb*512 + bid*8 + pjl];

  for (int t = 0; t < 128; ++t) {
    float s;
    if (t == 0) {
      s = gates0[rb*2048 + rcolg];
    } else {
      if (wvi == 0) poll_flags64(flags, (uint32_t)t);
      __syncthreads();                                       // (A)
      const uint64_t* hg = (const uint64_t*)(h_ex + (t & 1)*8192);
      #pragma unroll
      for (int q = 0; q < 8; ++q) {
        int u = q*512 + tid;
        uint64_t v = ld_u64_agent(&hg[u]);
        int bid2 = u >> 6, rem = u & 63, bb = rem >> 2, jh = rem & 3;
        *(uint64_t*)&h_lds[bb*520 + bid2*8 + jh*2] = v;
      }
      __syncthreads();                                       // (B)
      #pragma unroll
      for (int b = 0; b < 16; ++b) {
        float s0=0.f,s1=0.f,s2=0.f,s3=0.f;
        #pragma unroll
        for (int i = 0; i < 8; ++i) {
          int kk = (i + ksl) & 7;
          f32x4 hv = *(const f32x4*)&h_lds[b*520 + ksl*32 + kk*4];
          s0 = __fmaf_rn(hv.x, wreg[i].x, s0);
          s1 = __fmaf_rn(hv.y, wreg[i].y, s1);
          s2 = __fmaf_rn(hv.z, wreg[i].z, s2);
          s3 = __fmaf_rn(hv.w, wreg[i].w, s3);
        }
        float v = (s0+s1)+(s2+s3);
        v += __shfl_xor(v, 32);
        if (lane < 32) red2[wvi*512 + b*32 + lane] = v;
      }
      __syncthreads();                                       // (C)
      s = bias_r;
      #pragma unroll
      for (int w = 0; w < 8; ++w) s += red2[w*512 + tid];
    }
    gate_lds[rb*33 + rcol] = s;
    __syncthreads();                                         // (D)
    if (tid < 128) {
      float gi = gate_lds[pb*33 +      pjl];
      float gf = gate_lds[pb*33 +  8 + pjl];
      float gg = gate_lds[pb*33 + 16 + pjl];
      float go = gate_lds[pb*33 + 24 + pjl];
      float cn = sigf(gf)*c_reg + sigf(gi)*tanh_f(gg);
      float hn = sigf(go)*tanh_f(cn);
      c_reg = cn;
      st_f32_agent(&h_ex[((t+1) & 1)*8192 + bid*128 + pb*8 + pjl], hn);
      h_out_l[tid] = hn;
      asm volatile("s_waitcnt vmcnt(0)" ::: "memory");
      if (lane == 0) st_u32_agent(&flags[bid*32 + wvi], (uint32_t)(t + 1));
    }
    __syncthreads();                                         // (E)
    if (tid >= 128 && tid < 256) {
      float hn = h_out_l[tid - 128];
      int jgl = bid*8 + ojl;
      dec_h[((size_t)t*16 + ob)*512 + jgl] = hn;
      dec_out[((size_t)(ob*128 + t))*1024 + jgl] = __float2bfloat16(hn);
    }
  }
}

// ---------------- batched attention over all (t,b) ----------------
__global__ __launch_bounds__(256) void k_attn(
    const float* __restrict__ dec_h, const float* __restrict__ enc_out,
    bf16* __restrict__ dOut)
{
  const int tid = threadIdx.x, bid = blockIdx.x;
  const int b = bid >> 3, t0 = (bid & 7)*16;
  __shared__ float h16[16*512];
  __shared__ float sc[16*512];
  #pragma unroll
  for (int q = 0; q < 8; ++q) {
    int fi = q*256 + tid;
    int tt = fi >> 7, e4 = (fi & 127)*4;
    *(f32x4*)&h16[tt*512 + e4] = *(const f32x4*)&dec_h[((size_t)(t0 + tt)*16 + b)*512 + e4];
  }
  __syncthreads();
  const float* encb = &enc_out[(size_t)b*512*512];
  for (int si = 0; si < 2; ++si) {
    int s = si*256 + tid;
    float a[16];
    #pragma unroll
    for (int tt=0;tt<16;++tt) a[tt]=0.f;
    for (int e4 = 0; e4 < 512; e4 += 4) {
      f32x4 ev = *(const f32x4*)&encb[(size_t)s*512 + e4];
      #pragma unroll
      for (int tt = 0; tt < 16; ++tt) {
        f32x4 hv = *(const f32x4*)&h16[tt*512 + e4];
        a[tt] += ev.x*hv.x + ev.y*hv.y + ev.z*hv.z + ev.w*hv.w;
      }
    }
    #pragma unroll
    for (int tt=0;tt<16;++tt) sc[tt*512 + s] = a[tt];
  }
  __syncthreads();
  {
    int wv = tid >> 6, lane = tid & 63;
    #pragma unroll
    for (int u = 0; u < 4; ++u) {
      int tt = wv*4 + u;
      float x[8];
      float m = -1e30f;
      #pragma unroll
      for (int i=0;i<8;++i){ x[i] = sc[tt*512 + i*64 + lane]; m = fmaxf(m, x[i]); }
      #pragma unroll
      for (int off=1; off<64; off<<=1) m = fmaxf(m, __shfl_xor(m, off));
      float sum = 0.f;
      #pragma unroll
      for (int i=0;i<8;++i){ x[i] = __expf(x[i]-m); sum += x[i]; }
      #pragma unroll
      for (int off=1; off<64; off<<=1) sum += __shfl_xor(sum, off);
      float inv = 1.f/sum;
      #pragma unroll
      for (int i=0;i<8;++i) sc[tt*512 + i*64 + lane] = x[i]*inv;
    }
  }
  __syncthreads();
  {
    int e0 = tid*2;
    float cx[16], cy[16];
    #pragma unroll
    for (int tt=0;tt<16;++tt){ cx[tt]=0.f; cy[tt]=0.f; }
    for (int s = 0; s < 512; ++s) {
      f32x2 ev = *(const f32x2*)&encb[(size_t)s*512 + e0];
      #pragma unroll
      for (int tt = 0; tt < 16; ++tt) {
        float aw = sc[tt*512 + s];
        cx[tt] += aw*ev.x; cy[tt] += aw*ev.y;
      }
    }
    #pragma unroll
    for (int tt = 0; tt < 16; ++tt) {
      size_t rowo = ((size_t)(b*128 + t0 + tt))*1024 + 512 + e0;
      alignas(4) bf16 tmp[2] = {__float2bfloat16(cx[tt]), __float2bfloat16(cy[tt])};
      *(uint32_t*)&dOut[rowo] = *(const uint32_t*)tmp;
    }
  }
}

// ---------------- host ----------------
extern "C" void kernel_launch(void* const* d_in, const int* in_sizes, int n_in,
                              void* d_out, int out_size, void* d_ws, size_t ws_size,
                              hipStream_t stream)
{
  const int*   enc_in = (const int*)d_in[0];
  const int*   dec_in = (const int*)d_in[1];
  const float* emb    = (const float*)d_in[2];
  const float* w_ih_e = (const float*)d_in[3];
  const float* w_hh_e = (const float*)d_in[4];
  const float* b_ih_e = (const float*)d_in[5];
  const float* b_hh_e = (const float*)d_in[6];
  const float* w_ih_d = (const float*)d_in[7];
  const float* w_hh_d = (const float*)d_in[8];
  const float* b_ih_d = (const float*)d_in[9];
  const float* b_hh_d = (const float*)d_in[10];
  const float* w_proj = (const float*)d_in[11];
  const float* b_proj = (const float*)d_in[12];
  float* out = (float*)d_out;

  char* ws = (char*)d_ws;
  size_t off = 0;
  auto alloc = [&](size_t bytes)->void* { void* p = ws + off; off += (bytes + 255) & ~(size_t)255; return p; };
  bf16*  Wp      = (bf16*)alloc(32000ull*1024*2);
  bf16*  Xe      = (bf16*)alloc(8192ull*512*2);
  bf16*  Wie     = (bf16*)alloc(2048ull*512*2);
  bf16*  GXe     = (bf16*)alloc(8192ull*2048*2);
  float* enc_out = (float*)alloc(16ull*512*512*4);
  float* dec_h   = (float*)alloc(128ull*16*512*4);
  bf16*  dOutB   = (bf16*)alloc(2048ull*1024*2);
  float* h_ex    = (float*)alloc(2*64*128*4);       // [2][64 blocks][128] exclusive lines
  float* c_g     = (float*)alloc(16*512*4);
  float* g0      = (float*)alloc(16*2048*4);
  uint32_t* flagsE = (uint32_t*)alloc(64*128);      // one 128B line per block
  uint32_t* flagsD = (uint32_t*)alloc(64*128);
  if (off > ws_size) return;  // workspace too small -> fail validation loudly

  (void)hipMemsetAsync(flagsE, 0, 64*128, stream);
  (void)hipMemsetAsync(flagsD, 0, 64*128, stream);

  k_convert<<<32000, 256, 0, stream>>>(w_proj, Wp, 32768000);
  k_convert<<<1024, 256, 0, stream>>>(w_ih_e, Wie, 1048576);
  k_embed<<<4096, 256, 0, stream>>>(enc_in, emb, Xe);
  // encoder input gates for all timesteps: GXe = Xe @ w_ih_e^T + (b_ih_e + b_hh_e)
  k_gemm<1><<<dim3(16, 64), 256, 0, stream>>>(Xe, Wie, b_ih_e, b_hh_e, GXe, 8192, 2048, 512);
  k_encoder<<<NBLK, 512, 0, stream>>>(GXe, w_hh_e, h_ex, c_g, enc_out, flagsE);
  // final encoder h lands in h_ex[0] (t=511 writes buf (512&1)=0), permuted layout
  k_gates0<<<256, 128, 0, stream>>>(dec_in, emb, h_ex, w_ih_d, w_hh_d, b_ih_d, b_hh_d, g0);
  k_decoder<<<NBLK, 512, 0, stream>>>(w_ih_d, w_hh_d, b_ih_d, b_hh_d, g0, h_ex, c_g, dec_h, dOutB, flagsD);
  k_attn<<<128, 256, 0, stream>>>(dec_h, enc_out, dOutB);
  // logits = dec_out @ w_proj^T + b_proj
  k_gemm<0><<<dim3(250, 16), 256, 0, stream>>>(dOutB, Wp, b_proj, nullptr, out, 2048, 32000, 1024);
}